// Round 4
// baseline (151.174 us; speedup 1.0000x reference)
//
#include <hip/hip_runtime.h>

// SoftHistogram: x (4,3,65536) fp32 in [0,255) -> per-slice 256-bin soft histogram,
// normalized over bins.
// Reference: centers c_b = DELTA*(b+0.5), DELTA = 255/256, half = DELTA/2.
//   k(x,b) = sigmoid(x - c_b + half) - sigmoid(x - c_b - half)
//          = sigmoid(x - DELTA*b) - sigmoid(x - DELTA*(b+1))   (half cancels exactly)
// Truncate to bins with |x/DELTA - b| <= RADIUS (e^-11.95 tail -> output err ~1e-7).

constexpr int SLICES = 12;      // 4 * 3
constexpr int LENGTH = 65536;
constexpr int BINS   = 256;
constexpr int RADIUS = 12;
constexpr int TPB    = 256;
constexpr int EPT    = 4;       // elements per thread (one float4)
constexpr int BPS    = LENGTH / (TPB * EPT);   // 64 blocks per slice

constexpr float DELTA   = 255.0f / 256.0f;     // 0.99609375 (exact in fp32)
constexpr float INVD    = 256.0f / 255.0f;     // 1.003921568...
constexpr float ESTEP   = 2.70768425254f;      // exp(255/256)

__global__ __launch_bounds__(TPB) void soft_hist_accum(const float* __restrict__ x,
                                                       float* __restrict__ gh) {
    __shared__ float hist[BINS];
    const int tid   = threadIdx.x;
    const int slice = blockIdx.x / BPS;
    const int blk   = blockIdx.x % BPS;
    hist[tid] = 0.0f;
    __syncthreads();

    // coalesced float4 load: 16B/lane
    const float4 v = reinterpret_cast<const float4*>(x + slice * LENGTH + blk * (TPB * EPT))[tid];
    const float xs[4] = {v.x, v.y, v.z, v.w};

#pragma unroll
    for (int e = 0; e < EPT; ++e) {
        const float xv = xs[e];
        const int j  = (int)(xv * INVD);       // floor(x/DELTA), x >= 0
        const int b0 = j - RADIUS;
        // u_b = e^{DELTA*b - x}; one exp per element, recurrence u *= e^DELTA
        float u  = __expf(DELTA * (float)b0 - xv);
        float sp = __builtin_amdgcn_rcpf(1.0f + u);   // sigmoid(x - DELTA*b0)
#pragma unroll
        for (int i = 0; i < 2 * RADIUS + 1; ++i) {
            const int b = b0 + i;
            u *= ESTEP;                                // e^{DELTA*(b+1) - x}
            const float s = __builtin_amdgcn_rcpf(1.0f + u);  // sigmoid(x - DELTA*(b+1))
            const float k = sp - s;
            sp = s;
            if ((unsigned)b < (unsigned)BINS)
                unsafeAtomicAdd(&hist[b], k);          // ds_add_f32
        }
    }
    __syncthreads();
    unsafeAtomicAdd(&gh[slice * BINS + tid], hist[tid]);   // global_atomic_add_f32
}

__global__ __launch_bounds__(BINS) void soft_hist_norm(const float* __restrict__ gh,
                                                       float* __restrict__ out) {
    __shared__ float red[BINS];
    const int tid   = threadIdx.x;
    const int slice = blockIdx.x;
    const float h = gh[slice * BINS + tid];
    red[tid] = h;
    __syncthreads();
    for (int s = BINS / 2; s > 0; s >>= 1) {
        if (tid < s) red[tid] += red[tid + s];
        __syncthreads();
    }
    out[slice * BINS + tid] = h / red[0];
}

extern "C" void kernel_launch(void* const* d_in, const int* in_sizes, int n_in,
                              void* d_out, int out_size, void* d_ws, size_t ws_size,
                              hipStream_t stream) {
    const float* x = (const float*)d_in[0];
    float* out = (float*)d_out;
    float* gh  = (float*)d_ws;              // 12*256 floats = 12 KB partial hists

    hipMemsetAsync(gh, 0, SLICES * BINS * sizeof(float), stream);
    soft_hist_accum<<<dim3(SLICES * BPS), TPB, 0, stream>>>(x, gh);
    soft_hist_norm<<<dim3(SLICES), BINS, 0, stream>>>(gh, out);
}

// Round 9
// 81.544 us; speedup vs baseline: 1.8539x; 1.8539x over previous
//
#include <hip/hip_runtime.h>

// SoftHistogram: x (4,3,65536) fp32 in [0,255) -> per-slice 256-bin soft histogram,
// normalized over bins.  k(x,b) = sigmoid(x - DELTA*b) - sigmoid(x - DELTA*(b+1)),
// DELTA = 255/256.  Truncated to |t - b| <= R (t = x/DELTA); R=6: uniform missing
// mass cancels in normalization, edge systematic ~6e-6 << 8.5e-5 threshold.
//
// R4 lesson: wave-wide ds_add_f32 (LDS float atomic) costs ~196 cy/op on gfx950
// (98 us for 1200 ops/CU, VALUBusy 3.7%).  This version privatizes: hist[lane][bin]
// in LDS (64 KB, 1 wave/block) -> plain ds_read+add+ds_write, race-free by
// construction, banks conflict-free in both scatter and reduce orientations.

constexpr int SLICES = 12;
constexpr int LENGTH = 65536;
constexpr int BINS   = 256;
constexpr int R      = 6;
constexpr int NB     = 2 * R + 1;          // 13 bins per element
constexpr int TPB    = 64;                 // one wave
constexpr int BPS    = 64;                 // blocks per slice -> grid 768
constexpr int EPB    = LENGTH / BPS;       // 1024 elements per block
constexpr int EPT    = EPB / TPB;          // 16 per thread
constexpr int QUADS  = EPT / 4;            // 4 float4 loads per thread

constexpr float DELTA = 255.0f / 256.0f;   // exact in fp32
constexpr float INVD  = 256.0f / 255.0f;
constexpr float ESTEP = 2.70768425254f;    // exp(255/256)

constexpr size_t PART_BYTES = size_t(SLICES) * BPS * BINS * sizeof(float);

template <bool ATOMIC>
__global__ __launch_bounds__(TPB) void soft_hist_accum(const float* __restrict__ x,
                                                       float* __restrict__ part) {
    __shared__ float hist[64 * BINS];      // hist[lane][bin], exactly 64 KB
    const int l = threadIdx.x;

    // zero 64 KB: 64 x ds_write_b128 per lane, linear (standard pattern)
    const float4 z{0.f, 0.f, 0.f, 0.f};
#pragma unroll
    for (int r = 0; r < 64; ++r)
        reinterpret_cast<float4*>(hist)[r * 64 + l] = z;
    __syncthreads();

    const int slice = blockIdx.x / BPS;
    const int blk   = blockIdx.x % BPS;
    const float* xb = x + slice * LENGTH + blk * EPB;
    float* mycol = hist + l * BINS;        // this lane's private column

#pragma unroll
    for (int q = 0; q < QUADS; ++q) {
        const float4 v = reinterpret_cast<const float4*>(xb)[q * TPB + l];
        float xs[4] = {v.x, v.y, v.z, v.w};
        float u[4], sp[4];
        int b0[4];
#pragma unroll
        for (int e = 0; e < 4; ++e) {
            const int j = (int)(xs[e] * INVD);     // anchor bin (±1 harmless at R=6)
            b0[e] = j - R;
            u[e]  = __expf(DELTA * (float)b0[e] - xs[e]);   // e^{DELTA*b0 - x}
            sp[e] = __builtin_amdgcn_rcpf(1.0f + u[e]);     // sigmoid(x - DELTA*b0)
        }
        // 13 steps x 4 independent elements: ILP hides ds_read latency
#pragma unroll
        for (int i = 0; i < NB; ++i) {
#pragma unroll
            for (int e = 0; e < 4; ++e) {
                u[e] *= ESTEP;
                const float s = __builtin_amdgcn_rcpf(1.0f + u[e]);
                const float k = sp[e] - s;
                sp[e] = s;
                const int  b  = b0[e] + i;
                const bool ok = (unsigned)b < (unsigned)BINS;
                mycol[ok ? b : 0] += ok ? k : 0.0f;   // non-atomic RMW, own column
            }
        }
    }
    __syncthreads();

    // reduce 64 columns; lane l owns bins {l, l+64, l+128, l+192} (bank = l%32, free)
    float a0 = 0.f, a1 = 0.f, a2 = 0.f, a3 = 0.f;
#pragma unroll 8
    for (int j = 0; j < 64; ++j) {
        const float* row = hist + j * BINS;
        a0 += row[l];
        a1 += row[l + 64];
        a2 += row[l + 128];
        a3 += row[l + 192];
    }

    if (ATOMIC) {
        float* g = part + slice * BINS;    // 12 KB gh, pre-zeroed by memset
        unsafeAtomicAdd(&g[l], a0);
        unsafeAtomicAdd(&g[l + 64], a1);
        unsafeAtomicAdd(&g[l + 128], a2);
        unsafeAtomicAdd(&g[l + 192], a3);
    } else {
        float* dst = part + (slice * BPS + blk) * BINS;   // per-block partial
        dst[l]       = a0;
        dst[l + 64]  = a1;
        dst[l + 128] = a2;
        dst[l + 192] = a3;
    }
}

template <int NPART>
__global__ __launch_bounds__(BINS) void soft_hist_norm(const float* __restrict__ part,
                                                       float* __restrict__ out) {
    __shared__ float red[BINS];
    const int b = threadIdx.x;
    const int s = blockIdx.x;
    float h = 0.f;
#pragma unroll 8
    for (int j = 0; j < NPART; ++j)
        h += part[(s * NPART + j) * BINS + b];   // coalesced across b
    red[b] = h;
    __syncthreads();
#pragma unroll
    for (int k = BINS / 2; k > 0; k >>= 1) {
        if (b < k) red[b] += red[b + k];
        __syncthreads();
    }
    out[s * BINS + b] = h / red[0];
}

extern "C" void kernel_launch(void* const* d_in, const int* in_sizes, int n_in,
                              void* d_out, int out_size, void* d_ws, size_t ws_size,
                              hipStream_t stream) {
    const float* x = (const float*)d_in[0];
    float* out = (float*)d_out;
    float* ws  = (float*)d_ws;

    if (ws_size >= PART_BYTES) {
        // 2 launches, no memset: plain partial stores + sum in norm
        soft_hist_accum<false><<<dim3(SLICES * BPS), TPB, 0, stream>>>(x, ws);
        soft_hist_norm<BPS><<<dim3(SLICES), BINS, 0, stream>>>(ws, out);
    } else {
        // fallback: tiny gh + global float atomics (proven path from R4)
        hipMemsetAsync(ws, 0, SLICES * BINS * sizeof(float), stream);
        soft_hist_accum<true><<<dim3(SLICES * BPS), TPB, 0, stream>>>(x, ws);
        soft_hist_norm<1><<<dim3(SLICES), BINS, 0, stream>>>(ws, out);
    }
}

// Round 10
// 69.883 us; speedup vs baseline: 2.1633x; 1.1669x over previous
//
#include <hip/hip_runtime.h>

// SoftHistogram: x (4,3,65536) fp32 in [0,255) -> per-slice 256-bin soft histogram,
// normalized over bins.  k(x,b) = sigmoid(x - DELTA*b) - sigmoid(x - DELTA*(b+1)),
// DELTA = 255/256.  16-bin window (covers >= +-6 bins; e^-6 tail cancels in the
// normalization; R9 measured absmax 3.05e-5 == R=12's, pure fp noise).
//
// R4 lesson: wave-wide ds_add_f32 atomic ~196 cy -> privatize hist[lane][bin].
// R9 lesson: scalar LDS RMW (26 DS ops/elem) at 2 waves/CU is latency-exposed
// (accum ~25-32 us).  This version: 4-aligned 16-bin window, k's accumulated in
// registers, RMW as 4x ds_read_b128 + 4x ds_write_b128 per element (8 DS ops,
// 3.25x fewer, 4x wider).  Reduce phase also b128 (lane l owns bins [4l,4l+4)).

constexpr int SLICES = 12;
constexpr int LENGTH = 65536;
constexpr int BINS   = 256;
constexpr int TPB    = 64;                 // one wave
constexpr int BPS    = 64;                 // blocks per slice -> grid 768
constexpr int EPB    = LENGTH / BPS;       // 1024 elements per block
constexpr int EPT    = EPB / TPB;          // 16 per thread
constexpr int QUADS  = EPT / 4;            // 4 float4 loads per thread

constexpr float DELTA = 255.0f / 256.0f;   // exact in fp32
constexpr float INVD  = 256.0f / 255.0f;
constexpr float ESTEP = 2.70768425254f;    // exp(255/256)

constexpr size_t PART_BYTES = size_t(SLICES) * BPS * BINS * sizeof(float);

template <bool ATOMIC>
__global__ __launch_bounds__(TPB) void soft_hist_accum(const float* __restrict__ x,
                                                       float* __restrict__ part) {
    __shared__ float hist[64 * BINS];      // hist[lane][bin], exactly 64 KB
    const int l = threadIdx.x;

    const float4 z{0.f, 0.f, 0.f, 0.f};
#pragma unroll
    for (int r = 0; r < 64; ++r)
        reinterpret_cast<float4*>(hist)[r * 64 + l] = z;
    __syncthreads();

    const int slice = blockIdx.x / BPS;
    const int blk   = blockIdx.x % BPS;
    const float* xb = x + slice * LENGTH + blk * EPB;
    float* mycol = hist + l * BINS;        // this lane's private column (1 KB stride)

#pragma unroll
    for (int q = 0; q < QUADS; ++q) {
        const float4 v = reinterpret_cast<const float4*>(xb)[q * TPB + l];
        const float xs[4] = {v.x, v.y, v.z, v.w};
#pragma unroll
        for (int e = 0; e < 4; ++e) {
            const float xv = xs[e];
            const int j = (int)(xv * INVD);            // floor(x/DELTA)
            int a = (j - 6) & ~3;                      // 4-aligned, window covers j+-6
            a = a < 0 ? 0 : (a > BINS - 16 ? BINS - 16 : a);
            float u  = __expf(DELTA * (float)a - xv);  // e^{DELTA*a - x}
            float sp = __builtin_amdgcn_rcpf(1.0f + u);
            float4 kv[4];
#pragma unroll
            for (int g = 0; g < 4; ++g) {              // 16 bins, registers only
                float kk[4];
#pragma unroll
                for (int t = 0; t < 4; ++t) {
                    u *= ESTEP;
                    const float s = __builtin_amdgcn_rcpf(1.0f + u);
                    kk[t] = sp - s;
                    sp = s;
                }
                kv[g] = float4{kk[0], kk[1], kk[2], kk[3]};
            }
            float4* cp = reinterpret_cast<float4*>(mycol + a);   // 16B-aligned
#pragma unroll
            for (int g = 0; g < 4; ++g) {              // 4x b128 RMW, own column
                float4 cur = cp[g];
                cur.x += kv[g].x; cur.y += kv[g].y;
                cur.z += kv[g].z; cur.w += kv[g].w;
                cp[g] = cur;
            }
        }
    }
    __syncthreads();

    // reduce 64 columns; lane l owns bins [4l, 4l+4): b128 reads, 8 lanes/bank = optimal
    float4 acc{0.f, 0.f, 0.f, 0.f};
#pragma unroll 8
    for (int j = 0; j < 64; ++j) {
        const float4 row = reinterpret_cast<const float4*>(hist + j * BINS)[l];
        acc.x += row.x; acc.y += row.y; acc.z += row.z; acc.w += row.w;
    }

    if (ATOMIC) {
        float* g = part + slice * BINS;    // 12 KB gh, pre-zeroed by memset
        unsafeAtomicAdd(&g[4 * l + 0], acc.x);
        unsafeAtomicAdd(&g[4 * l + 1], acc.y);
        unsafeAtomicAdd(&g[4 * l + 2], acc.z);
        unsafeAtomicAdd(&g[4 * l + 3], acc.w);
    } else {
        float4* dst = reinterpret_cast<float4*>(part + (slice * BPS + blk) * BINS);
        dst[l] = acc;                      // coalesced 16B/lane per-block partial
    }
}

template <int NPART>
__global__ __launch_bounds__(BINS) void soft_hist_norm(const float* __restrict__ part,
                                                       float* __restrict__ out) {
    __shared__ float red[BINS];
    const int b = threadIdx.x;
    const int s = blockIdx.x;
    float h = 0.f;
#pragma unroll 8
    for (int j = 0; j < NPART; ++j)
        h += part[(s * NPART + j) * BINS + b];   // coalesced across b
    red[b] = h;
    __syncthreads();
#pragma unroll
    for (int k = BINS / 2; k > 0; k >>= 1) {
        if (b < k) red[b] += red[b + k];
        __syncthreads();
    }
    out[s * BINS + b] = h / red[0];
}

extern "C" void kernel_launch(void* const* d_in, const int* in_sizes, int n_in,
                              void* d_out, int out_size, void* d_ws, size_t ws_size,
                              hipStream_t stream) {
    const float* x = (const float*)d_in[0];
    float* out = (float*)d_out;
    float* ws  = (float*)d_ws;

    if (ws_size >= PART_BYTES) {
        // 2 launches, no memset: plain partial stores + sum in norm
        soft_hist_accum<false><<<dim3(SLICES * BPS), TPB, 0, stream>>>(x, ws);
        soft_hist_norm<BPS><<<dim3(SLICES), BINS, 0, stream>>>(ws, out);
    } else {
        // fallback: tiny gh + global float atomics
        hipMemsetAsync(ws, 0, SLICES * BINS * sizeof(float), stream);
        soft_hist_accum<true><<<dim3(SLICES * BPS), TPB, 0, stream>>>(x, ws);
        soft_hist_norm<1><<<dim3(SLICES), BINS, 0, stream>>>(ws, out);
    }
}

// Round 11
// 64.034 us; speedup vs baseline: 2.3608x; 1.0913x over previous
//
#include <hip/hip_runtime.h>

// SoftHistogram: x (4,3,65536) fp32 in [0,255) -> per-slice 256-bin soft histogram,
// normalized over bins.  k(x,b) = sigmoid(x - DELTA*b) - sigmoid(x - DELTA*(b+1)),
// DELTA = 255/256.  16-bin 4-aligned window covers +-6 bins (e^-6 uniform tail
// cancels in normalization; R9/R10 measured absmax identical to R=12).
//
// Ladder: R4 ds_add_f32 atomics ~49cy/op, accum 98us -> R10 f32 privatized b128 RMW,
// accum ~19us (64KB LDS = 2/CU resident vs 3 needed; dependent RMW chains expose
// ~120cy LDS latency).  R11: u16 fixed-point hist (32KB -> 3/CU co-resident),
// round(k*4096)<=1893, 16 adds/bin max = 30288 < 65536 -> packed u16 adds carry-free
// as plain u32 adds; scale cancels in h/sum(h).  RMW batched read4->add->write4.

constexpr int SLICES = 12;
constexpr int LENGTH = 65536;
constexpr int BINS   = 256;
constexpr int TPB    = 64;                 // one wave
constexpr int BPS    = 64;                 // blocks per slice -> grid 768 = 3/CU exact
constexpr int EPB    = LENGTH / BPS;       // 1024 elements per block
constexpr int EPT    = EPB / TPB;          // 16 per thread
constexpr int QUADS  = EPT / 4;            // 4 float4 loads per thread

constexpr float DELTA  = 255.0f / 256.0f;  // exact in fp32
constexpr float INVD   = 256.0f / 255.0f;
constexpr float ESTEP  = 2.70768425254f;   // exp(255/256)
constexpr float QSCALE = 4096.0f;          // cancels in normalization

constexpr size_t PART_BYTES = size_t(SLICES) * BPS * BINS * sizeof(float);

template <bool ATOMIC>
__global__ __launch_bounds__(TPB) void soft_hist_accum(const float* __restrict__ x,
                                                       float* __restrict__ part) {
    __shared__ unsigned short hist[64 * BINS];   // hist[lane][bin], 32 KB u16
    const int l = threadIdx.x;

    // zero 32 KB: 32 x b128 per lane
    uint4* hz = reinterpret_cast<uint4*>(hist);
    const uint4 z4{0u, 0u, 0u, 0u};
#pragma unroll
    for (int r = 0; r < 32; ++r)
        hz[r * 64 + l] = z4;
    __syncthreads();

    const int slice = blockIdx.x / BPS;
    const int blk   = blockIdx.x % BPS;
    const float* xb = x + slice * LENGTH + blk * EPB;
    unsigned short* mycol = hist + l * BINS;     // 512 B stride, lane-private

#pragma unroll
    for (int q = 0; q < QUADS; ++q) {
        const float4 v = reinterpret_cast<const float4*>(xb)[q * TPB + l];
        const float xs[4] = {v.x, v.y, v.z, v.w};
#pragma unroll
        for (int e = 0; e < 4; ++e) {
            const float xv = xs[e];
            const int j = (int)(xv * INVD);      // floor(x/DELTA)
            int a = (j - 6) & ~3;                // 4-aligned, covers j+-6
            a = a < 0 ? 0 : (a > BINS - 16 ? BINS - 16 : a);
            float u  = __expf(DELTA * (float)a - xv);
            float sp = __builtin_amdgcn_rcpf(1.0f + u);
            unsigned int pk[8];                  // 16 bins -> 8 packed u16x2
#pragma unroll
            for (int g = 0; g < 8; ++g) {
                u *= ESTEP;
                const float s0 = __builtin_amdgcn_rcpf(1.0f + u);
                const unsigned int q0 = (unsigned int)((sp - s0) * QSCALE + 0.5f);
                sp = s0;
                u *= ESTEP;
                const float s1 = __builtin_amdgcn_rcpf(1.0f + u);
                const unsigned int q1 = (unsigned int)((sp - s1) * QSCALE + 0.5f);
                sp = s1;
                pk[g] = q0 | (q1 << 16);
            }
            uint2* cp = reinterpret_cast<uint2*>(mycol + a);   // 8B-aligned (a%4==0)
            // batched RMW: all reads -> all adds -> all writes (one latency, not four)
            uint2 c0 = cp[0], c1 = cp[1], c2 = cp[2], c3 = cp[3];
            c0.x += pk[0]; c0.y += pk[1];
            c1.x += pk[2]; c1.y += pk[3];
            c2.x += pk[4]; c2.y += pk[5];
            c3.x += pk[6]; c3.y += pk[7];
            cp[0] = c0; cp[1] = c1; cp[2] = c2; cp[3] = c3;
        }
    }
    __syncthreads();

    // reduce: lane l owns bins [4l,4l+4); uint2 (4 u16) per column; exact u32 sums
    unsigned int a0 = 0, a1 = 0, a2 = 0, a3 = 0;
#pragma unroll 8
    for (int jj = 0; jj < 64; ++jj) {
        const uint2 c = *reinterpret_cast<const uint2*>(hist + jj * BINS + 4 * l);
        a0 += c.x & 0xFFFFu; a1 += c.x >> 16;
        a2 += c.y & 0xFFFFu; a3 += c.y >> 16;
    }
    // per-block-bin sums <= 64*30288 < 2^24 -> float conversion exact
    if (ATOMIC) {
        float* g = part + slice * BINS;
        unsafeAtomicAdd(&g[4 * l + 0], (float)a0);
        unsafeAtomicAdd(&g[4 * l + 1], (float)a1);
        unsafeAtomicAdd(&g[4 * l + 2], (float)a2);
        unsafeAtomicAdd(&g[4 * l + 3], (float)a3);
    } else {
        float4* dst = reinterpret_cast<float4*>(part + (slice * BPS + blk) * BINS);
        dst[l] = float4{(float)a0, (float)a1, (float)a2, (float)a3};
    }
}

template <int NPART>
__global__ __launch_bounds__(BINS) void soft_hist_norm(const float* __restrict__ part,
                                                       float* __restrict__ out) {
    __shared__ float red[BINS];
    const int b = threadIdx.x;
    const int s = blockIdx.x;
    float h = 0.f;
#pragma unroll 8
    for (int j = 0; j < NPART; ++j)
        h += part[(s * NPART + j) * BINS + b];   // coalesced across b
    red[b] = h;
    __syncthreads();
#pragma unroll
    for (int k = BINS / 2; k > 0; k >>= 1) {
        if (b < k) red[b] += red[b + k];
        __syncthreads();
    }
    out[s * BINS + b] = h / red[0];              // QSCALE cancels here
}

extern "C" void kernel_launch(void* const* d_in, const int* in_sizes, int n_in,
                              void* d_out, int out_size, void* d_ws, size_t ws_size,
                              hipStream_t stream) {
    const float* x = (const float*)d_in[0];
    float* out = (float*)d_out;
    float* ws  = (float*)d_ws;

    if (ws_size >= PART_BYTES) {
        // 2 launches, no memset: per-block partials + sum in norm
        soft_hist_accum<false><<<dim3(SLICES * BPS), TPB, 0, stream>>>(x, ws);
        soft_hist_norm<BPS><<<dim3(SLICES), BINS, 0, stream>>>(ws, out);
    } else {
        // fallback: tiny gh + global float atomics
        hipMemsetAsync(ws, 0, SLICES * BINS * sizeof(float), stream);
        soft_hist_accum<true><<<dim3(SLICES * BPS), TPB, 0, stream>>>(x, ws);
        soft_hist_norm<1><<<dim3(SLICES), BINS, 0, stream>>>(ws, out);
    }
}

// Round 12
// 63.043 us; speedup vs baseline: 2.3980x; 1.0157x over previous
//
#include <hip/hip_runtime.h>

// SoftHistogram: x (4,3,65536) fp32 in [0,255) -> per-slice 256-bin soft histogram,
// normalized over bins.  k(x,b) = sigmoid(x - DELTA*b) - sigmoid(x - DELTA*(b+1)),
// DELTA = 255/256.  16-bin 4-aligned window covers +-6 bins (uniform tail cancels
// in normalization; R9-R11 absmax identical to full-width).
//
// Ladder: R4 ds_add_f32 atomics (accum 98us) -> R10 f32 privatized b128 RMW (~19us,
// 2/CU resident) -> R11 u16 packed hist 32KB, 3/CU (~11us).  R12: hide LDS read
// latency under TRANS compute (reads issued BEFORE sigmoid calc) and kill the
// 16-deep serial u*=E chain via u_i = u0*E^i table (all rcps independent).

constexpr int SLICES = 12;
constexpr int LENGTH = 65536;
constexpr int BINS   = 256;
constexpr int TPB    = 64;                 // one wave
constexpr int BPS    = 64;                 // blocks per slice -> grid 768 = 3/CU
constexpr int EPB    = LENGTH / BPS;       // 1024 elements per block
constexpr int EPT    = EPB / TPB;          // 16 per thread
constexpr int QUADS  = EPT / 4;            // 4 float4 loads per thread

constexpr float DELTA  = 255.0f / 256.0f;  // exact in fp32
constexpr float INVD   = 256.0f / 255.0f;
constexpr float QSCALE = 4096.0f;          // cancels in normalization

// POWT[i-1] = exp(i * DELTA), i = 1..16  (checked vs e^i/e^{i/256}, rel err ~1e-6;
// resulting k error ~5e-6 << 1/QSCALE quant step)
__device__ constexpr float POWT[16] = {
    2.70768428e+00f, 7.33155410e+00f, 1.98515320e+01f, 5.37516860e+01f,
    1.45542600e+02f, 3.94083320e+02f, 1.06705320e+03f, 2.88924370e+03f,
    7.82316000e+03f, 2.11826300e+04f, 5.73559200e+04f, 1.55301660e+05f,
    4.20508100e+05f, 1.13860250e+06f, 3.08297300e+06f, 8.34772400e+06f};

constexpr size_t PART_BYTES = size_t(SLICES) * BPS * BINS * sizeof(float);

template <bool ATOMIC>
__global__ __launch_bounds__(TPB) void soft_hist_accum(const float* __restrict__ x,
                                                       float* __restrict__ part) {
    __shared__ unsigned short hist[64 * BINS];   // hist[lane][bin], 32 KB u16
    const int l = threadIdx.x;

    uint4* hz = reinterpret_cast<uint4*>(hist);
    const uint4 z4{0u, 0u, 0u, 0u};
#pragma unroll
    for (int r = 0; r < 32; ++r)
        hz[r * 64 + l] = z4;
    __syncthreads();

    const int slice = blockIdx.x / BPS;
    const int blk   = blockIdx.x % BPS;
    const float* xb = x + slice * LENGTH + blk * EPB;
    unsigned short* mycol = hist + l * BINS;     // 512 B stride, lane-private

#pragma unroll
    for (int q = 0; q < QUADS; ++q) {
        const float4 v = reinterpret_cast<const float4*>(xb)[q * TPB + l];
        const float xs[4] = {v.x, v.y, v.z, v.w};
#pragma unroll
        for (int e = 0; e < 4; ++e) {
            const float xv = xs[e];
            const int j = (int)(xv * INVD);      // floor(x/DELTA)
            int a = (j - 6) & ~3;                // 4-aligned, covers j+-6
            a = a < 0 ? 0 : (a > BINS - 16 ? BINS - 16 : a);
            // 1) issue window reads FIRST (latency hides under trans compute below)
            uint2* cp = reinterpret_cast<uint2*>(mycol + a);   // 8B-aligned
            uint2 c0 = cp[0], c1 = cp[1], c2 = cp[2], c3 = cp[3];
            // 2) 17 sigmoids, all independent: u_i = u0 * E^i
            const float u0 = __expf(fmaf(DELTA, (float)a, -xv));  // e^{DELTA*a - x}
            float s[17];
            s[0] = __builtin_amdgcn_rcpf(1.0f + u0);
#pragma unroll
            for (int i = 1; i <= 16; ++i)
                s[i] = __builtin_amdgcn_rcpf(fmaf(u0, POWT[i - 1], 1.0f));
            // 3) quantize + pack u16x2
            unsigned int pk[8];
#pragma unroll
            for (int g = 0; g < 8; ++g) {
                const unsigned int q0 =
                    (unsigned int)fmaf(s[2 * g] - s[2 * g + 1], QSCALE, 0.5f);
                const unsigned int q1 =
                    (unsigned int)fmaf(s[2 * g + 1] - s[2 * g + 2], QSCALE, 0.5f);
                pk[g] = q0 | (q1 << 16);
            }
            // 4) carry-free packed add (max 16*1000 < 65536), write back
            c0.x += pk[0]; c0.y += pk[1]; c1.x += pk[2]; c1.y += pk[3];
            c2.x += pk[4]; c2.y += pk[5]; c3.x += pk[6]; c3.y += pk[7];
            cp[0] = c0; cp[1] = c1; cp[2] = c2; cp[3] = c3;
        }
    }
    __syncthreads();

    // reduce: lane l owns bins [4l,4l+4); exact u32 sums (< 2^24 -> float exact)
    unsigned int a0 = 0, a1 = 0, a2 = 0, a3 = 0;
#pragma unroll 8
    for (int jj = 0; jj < 64; ++jj) {
        const uint2 c = *reinterpret_cast<const uint2*>(hist + jj * BINS + 4 * l);
        a0 += c.x & 0xFFFFu; a1 += c.x >> 16;
        a2 += c.y & 0xFFFFu; a3 += c.y >> 16;
    }
    if (ATOMIC) {
        float* g = part + slice * BINS;
        unsafeAtomicAdd(&g[4 * l + 0], (float)a0);
        unsafeAtomicAdd(&g[4 * l + 1], (float)a1);
        unsafeAtomicAdd(&g[4 * l + 2], (float)a2);
        unsafeAtomicAdd(&g[4 * l + 3], (float)a3);
    } else {
        float4* dst = reinterpret_cast<float4*>(part + (slice * BPS + blk) * BINS);
        dst[l] = float4{(float)a0, (float)a1, (float)a2, (float)a3};
    }
}

template <int NPART>
__global__ __launch_bounds__(BINS) void soft_hist_norm(const float* __restrict__ part,
                                                       float* __restrict__ out) {
    __shared__ float wsum[4];
    const int b = threadIdx.x;
    const int s = blockIdx.x;
    float h = 0.f;
#pragma unroll 8
    for (int j = 0; j < NPART; ++j)
        h += part[(s * NPART + j) * BINS + b];   // coalesced across b
    // 64-lane shuffle reduce + 4-word cross-wave combine (replaces 8-barrier tree)
    float t = h;
#pragma unroll
    for (int m = 1; m < 64; m <<= 1)
        t += __shfl_xor(t, m, 64);
    if ((b & 63) == 0) wsum[b >> 6] = t;
    __syncthreads();
    const float Z = wsum[0] + wsum[1] + wsum[2] + wsum[3];
    out[s * BINS + b] = h / Z;                   // QSCALE cancels here
}

extern "C" void kernel_launch(void* const* d_in, const int* in_sizes, int n_in,
                              void* d_out, int out_size, void* d_ws, size_t ws_size,
                              hipStream_t stream) {
    const float* x = (const float*)d_in[0];
    float* out = (float*)d_out;
    float* ws  = (float*)d_ws;

    if (ws_size >= PART_BYTES) {
        // 2 launches, no memset: per-block partials + sum in norm
        soft_hist_accum<false><<<dim3(SLICES * BPS), TPB, 0, stream>>>(x, ws);
        soft_hist_norm<BPS><<<dim3(SLICES), BINS, 0, stream>>>(ws, out);
    } else {
        // fallback: tiny gh + global float atomics
        hipMemsetAsync(ws, 0, SLICES * BINS * sizeof(float), stream);
        soft_hist_accum<true><<<dim3(SLICES * BPS), TPB, 0, stream>>>(x, ws);
        soft_hist_norm<1><<<dim3(SLICES), BINS, 0, stream>>>(ws, out);
    }
}

// Round 13
// 62.490 us; speedup vs baseline: 2.4192x; 1.0089x over previous
//
#include <hip/hip_runtime.h>

// SoftHistogram: x (4,3,65536) fp32 in [0,255) -> per-slice 256-bin soft histogram,
// normalized over bins.  k(x,b) = sigmoid(x - DELTA*b) - sigmoid(x - DELTA*(b+1)),
// DELTA = 255/256.  16-bin 4-aligned window covers +-6 bins (uniform tail cancels
// in normalization; R9-R12 absmax identical to full-width = comparison floor).
//
// Ladder: R4 ds_add_f32 atomics (accum 98us) -> R10 f32 privatized b128 RMW (~19us)
// -> R11 u16 packed hist 32KB, 3 blk/CU (~11us) -> R12 POWT table (independent rcps).
// R13: explicit global prefetch (quad q+1 issued before processing quad q) and
// pairwise-packed reduce (c_j + c_{j+1} carry-free: 2*30288 < 65536, halves unpack).

constexpr int SLICES = 12;
constexpr int LENGTH = 65536;
constexpr int BINS   = 256;
constexpr int TPB    = 64;                 // one wave
constexpr int BPS    = 64;                 // blocks per slice -> grid 768 = 3/CU
constexpr int EPB    = LENGTH / BPS;       // 1024 elements per block
constexpr int EPT    = EPB / TPB;          // 16 per thread
constexpr int QUADS  = EPT / 4;            // 4 float4 loads per thread

constexpr float DELTA  = 255.0f / 256.0f;  // exact in fp32
constexpr float INVD   = 256.0f / 255.0f;
constexpr float QSCALE = 4096.0f;          // cancels in normalization

// POWT[i-1] = exp(i * DELTA), i = 1..16 (rel err ~1e-6; k err << 1/QSCALE)
__device__ constexpr float POWT[16] = {
    2.70768428e+00f, 7.33155410e+00f, 1.98515320e+01f, 5.37516860e+01f,
    1.45542600e+02f, 3.94083320e+02f, 1.06705320e+03f, 2.88924370e+03f,
    7.82316000e+03f, 2.11826300e+04f, 5.73559200e+04f, 1.55301660e+05f,
    4.20508100e+05f, 1.13860250e+06f, 3.08297300e+06f, 8.34772400e+06f};

constexpr size_t PART_BYTES = size_t(SLICES) * BPS * BINS * sizeof(float);

template <bool ATOMIC>
__global__ __launch_bounds__(TPB) void soft_hist_accum(const float* __restrict__ x,
                                                       float* __restrict__ part) {
    __shared__ unsigned short hist[64 * BINS];   // hist[lane][bin], 32 KB u16
    const int l = threadIdx.x;

    uint4* hz = reinterpret_cast<uint4*>(hist);
    const uint4 z4{0u, 0u, 0u, 0u};
#pragma unroll
    for (int r = 0; r < 32; ++r)
        hz[r * 64 + l] = z4;
    __syncthreads();

    const int slice = blockIdx.x / BPS;
    const int blk   = blockIdx.x % BPS;
    const float4* xq = reinterpret_cast<const float4*>(x + slice * LENGTH + blk * EPB);
    unsigned short* mycol = hist + l * BINS;     // 512 B stride, lane-private

    float4 v = xq[l];                            // prefetch quad 0
#pragma unroll
    for (int q = 0; q < QUADS; ++q) {
        const float4 cur = v;
        if (q + 1 < QUADS)
            v = xq[(q + 1) * TPB + l];           // prefetch next quad early
        const float xs[4] = {cur.x, cur.y, cur.z, cur.w};
#pragma unroll
        for (int e = 0; e < 4; ++e) {
            const float xv = xs[e];
            const int j = (int)(xv * INVD);      // floor(x/DELTA)
            int a = (j - 6) & ~3;                // 4-aligned, covers j+-6
            a = a < 0 ? 0 : (a > BINS - 16 ? BINS - 16 : a);
            // issue window reads first (latency hides under trans compute)
            uint2* cp = reinterpret_cast<uint2*>(mycol + a);   // 8B-aligned
            uint2 c0 = cp[0], c1 = cp[1], c2 = cp[2], c3 = cp[3];
            // 17 independent sigmoids: u_i = u0 * E^i
            const float u0 = __expf(fmaf(DELTA, (float)a, -xv));
            float s[17];
            s[0] = __builtin_amdgcn_rcpf(1.0f + u0);
#pragma unroll
            for (int i = 1; i <= 16; ++i)
                s[i] = __builtin_amdgcn_rcpf(fmaf(u0, POWT[i - 1], 1.0f));
            // quantize + pack u16x2
            unsigned int pk[8];
#pragma unroll
            for (int g = 0; g < 8; ++g) {
                const unsigned int q0 =
                    (unsigned int)fmaf(s[2 * g] - s[2 * g + 1], QSCALE, 0.5f);
                const unsigned int q1 =
                    (unsigned int)fmaf(s[2 * g + 1] - s[2 * g + 2], QSCALE, 0.5f);
                pk[g] = q0 | (q1 << 16);
            }
            // carry-free packed add (max 16*1893 = 30288 < 65536), write back
            c0.x += pk[0]; c0.y += pk[1]; c1.x += pk[2]; c1.y += pk[3];
            c2.x += pk[4]; c2.y += pk[5]; c3.x += pk[6]; c3.y += pk[7];
            cp[0] = c0; cp[1] = c1; cp[2] = c2; cp[3] = c3;
        }
    }
    __syncthreads();

    // reduce: lane l owns bins [4l,4l+4).  Pairwise packed add first (2 columns
    // carry-free: 2*30288 < 65536), then unpack -> halves unpack VALU.
    unsigned int a0 = 0, a1 = 0, a2 = 0, a3 = 0;
#pragma unroll 8
    for (int jj = 0; jj < 64; jj += 2) {
        const uint2 c = *reinterpret_cast<const uint2*>(hist + jj * BINS + 4 * l);
        const uint2 d = *reinterpret_cast<const uint2*>(hist + (jj + 1) * BINS + 4 * l);
        const unsigned int sx = c.x + d.x;       // packed u16x2, no carry
        const unsigned int sy = c.y + d.y;
        a0 += sx & 0xFFFFu; a1 += sx >> 16;
        a2 += sy & 0xFFFFu; a3 += sy >> 16;
    }
    // per-block-bin sums <= 64*30288 < 2^24 -> float conversion exact
    if (ATOMIC) {
        float* g = part + slice * BINS;
        unsafeAtomicAdd(&g[4 * l + 0], (float)a0);
        unsafeAtomicAdd(&g[4 * l + 1], (float)a1);
        unsafeAtomicAdd(&g[4 * l + 2], (float)a2);
        unsafeAtomicAdd(&g[4 * l + 3], (float)a3);
    } else {
        float4* dst = reinterpret_cast<float4*>(part + (slice * BPS + blk) * BINS);
        dst[l] = float4{(float)a0, (float)a1, (float)a2, (float)a3};
    }
}

template <int NPART>
__global__ __launch_bounds__(BINS) void soft_hist_norm(const float* __restrict__ part,
                                                       float* __restrict__ out) {
    __shared__ float wsum[4];
    const int b = threadIdx.x;
    const int s = blockIdx.x;
    float h = 0.f;
#pragma unroll 8
    for (int j = 0; j < NPART; ++j)
        h += part[(s * NPART + j) * BINS + b];   // coalesced across b
    float t = h;
#pragma unroll
    for (int m = 1; m < 64; m <<= 1)
        t += __shfl_xor(t, m, 64);
    if ((b & 63) == 0) wsum[b >> 6] = t;
    __syncthreads();
    const float Z = wsum[0] + wsum[1] + wsum[2] + wsum[3];
    out[s * BINS + b] = h / Z;                   // QSCALE cancels here
}

extern "C" void kernel_launch(void* const* d_in, const int* in_sizes, int n_in,
                              void* d_out, int out_size, void* d_ws, size_t ws_size,
                              hipStream_t stream) {
    const float* x = (const float*)d_in[0];
    float* out = (float*)d_out;
    float* ws  = (float*)d_ws;

    if (ws_size >= PART_BYTES) {
        // 2 launches, no memset: per-block partials + sum in norm
        soft_hist_accum<false><<<dim3(SLICES * BPS), TPB, 0, stream>>>(x, ws);
        soft_hist_norm<BPS><<<dim3(SLICES), BINS, 0, stream>>>(ws, out);
    } else {
        // fallback: tiny gh + global float atomics
        hipMemsetAsync(ws, 0, SLICES * BINS * sizeof(float), stream);
        soft_hist_accum<true><<<dim3(SLICES * BPS), TPB, 0, stream>>>(x, ws);
        soft_hist_norm<1><<<dim3(SLICES), BINS, 0, stream>>>(ws, out);
    }
}